// Round 12
// baseline (262.845 us; speedup 1.0000x reference)
//
#include <hip/hip_runtime.h>
#include <hip/hip_bf16.h>

#define BB 4
#define NN 200
#define HH 300
#define NCH 10            // k-steps of 32 (K padded to 320)
#define GHF 10            // g-frags of 16 per g-half (G padded to 320)

typedef __attribute__((ext_vector_type(8))) short short8;
typedef __attribute__((ext_vector_type(4))) float float4v;

static __device__ __forceinline__ ushort f2bf(float x) {
    union { float f; uint u; } v; v.f = x;
    uint r = v.u + 0x7FFFu + ((v.u >> 16) & 1u);  // RNE
    return (ushort)(r >> 16);
}

// 8 f32 -> 8 bf16 (RNE) via v_cvt_pk_bf16_f32
static __device__ __forceinline__ short8 pack8_cvt(float4v a, float4v b) {
    uint u0, u1, u2, u3;
    asm("v_cvt_pk_bf16_f32 %0, %1, %2" : "=v"(u0) : "v"(a[0]), "v"(a[1]));
    asm("v_cvt_pk_bf16_f32 %0, %1, %2" : "=v"(u1) : "v"(a[2]), "v"(a[3]));
    asm("v_cvt_pk_bf16_f32 %0, %1, %2" : "=v"(u2) : "v"(b[0]), "v"(b[1]));
    asm("v_cvt_pk_bf16_f32 %0, %1, %2" : "=v"(u3) : "v"(b[2]), "v"(b[3]));
    union { uint u[4]; short8 s; } r;
    r.u[0] = u0; r.u[1] = u1; r.u[2] = u2; r.u[3] = u3;
    return r.s;
}

// Pack U_w (g,h) f32 -> bf16 frag order, g-half-major:
// off(ushorts) = gh*51200 + ks*5120 + fh*512 + lane*8
// elem j: g=(gh*GHF+fh)*16+(lane&15), h=ks*32+(lane>>4)*8+j, 0 if OOB
__global__ void pack_u(const float* __restrict__ Uw, ushort* __restrict__ Bp) {
    int idx = blockIdx.x * 256 + threadIdx.x;
    if (idx >= 2 * NCH * GHF * 64) return;
    int lane = idx & 63;
    int rem = idx >> 6;
    int fh = rem % GHF;
    int ks = (rem / GHF) % NCH;
    int gh = rem / (GHF * NCH);
    int g = (gh * GHF + fh) * 16 + (lane & 15);
    int h0 = ks * 32 + (lane >> 4) * 8;
    ushort v[8];
#pragma unroll
    for (int j = 0; j < 8; ++j) {
        int h = h0 + j;
        v[j] = (g < HH && h < HH) ? f2bf(Uw[g * HH + h]) : (ushort)0;
    }
    *reinterpret_cast<short8*>(Bp + (size_t)idx * 8) = *reinterpret_cast<const short8*>(v);
}

// Vx[b,n,g] = sum_h x[b,n,h]*Vw[g,h] + Vb[g] + 0.5*Ub[g]   (Ub folded)
__global__ void vx_kernel(const float* __restrict__ x, const float* __restrict__ Vw,
                          const float* __restrict__ Vb, const float* __restrict__ Ub,
                          float* __restrict__ Vx) {
    __shared__ float xs[HH];
    int row = blockIdx.x;
    const float* xr = x + (size_t)row * HH;
    for (int h = threadIdx.x; h < HH; h += 256) xs[h] = xr[h];
    __syncthreads();
    for (int g = threadIdx.x; g < HH; g += 256) {
        const float4* wr = reinterpret_cast<const float4*>(Vw + (size_t)g * HH);
        const float4* xv = reinterpret_cast<const float4*>(xs);
        float s0 = 0.f, s1 = 0.f, s2 = 0.f, s3 = 0.f;
#pragma unroll 5
        for (int k = 0; k < HH / 4; ++k) {
            float4 w = wr[k];
            float4 xx = xv[k];
            s0 += w.x * xx.x; s1 += w.y * xx.y; s2 += w.z * xx.z; s3 += w.w * xx.w;
        }
        Vx[(size_t)row * HH + g] = Vb[g] + 0.5f * Ub[g] + s0 + s1 + s2 + s3;
    }
}

// Free-running, LDS-free, barrier-free: each wave owns one (32-row x g-half) tile.
// task = blockIdx*4 + wave; gh = task&1 (twin g-halves share the block -> L1 reuse
// of the same 32 e-rows). A: per-lane frag loads (16-row pattern), 1-deep prefetch.
// B: frag-packed U_w read directly from L2 (1 KB/instr coalesced). Swapped-operand
// MFMA (R7-proven): acc reg-index = g quad, lane&15 = row -> float4 stores.
__launch_bounds__(256, 4)
__global__ void gemm_kernel(const float* __restrict__ e, const ushort* __restrict__ Bp,
                            const float* __restrict__ Vx, float* __restrict__ out) {
    const int tid = threadIdx.x;
    const int lane = tid & 63, wave = tid >> 6;
    const int task = blockIdx.x * 4 + wave;   // 0..9999
    const int gh = task & 1;
    const int tile = task >> 1;               // 0..4999
    const int m0 = tile * 32;
    const int r = lane & 15, q = lane >> 4, kq = q * 8;

    const float* rowA = e + (size_t)(m0 + r) * HH;
    const float* rowB = rowA + 16 * HH;
    const ushort* bb = Bp + (size_t)gh * (NCH * GHF * 512);

    float4v acc0[GHF], acc1[GHF];
#pragma unroll
    for (int f = 0; f < GHF; ++f) {
        acc0[f] = (float4v){0.f, 0.f, 0.f, 0.f};
        acc1[f] = (float4v){0.f, 0.f, 0.f, 0.f};
    }

    float4v a0, a1, b0, b1;   // single A reg set (TLP hides latency at 16 waves/CU)

#define LOAD_A(K_) do {                                                         \
        int c0_ = (K_) * 32 + kq;                                               \
        const float* p0_ = (c0_ + 4 <= HH) ? rowA + c0_ : e;                    \
        const float* p1_ = (c0_ + 8 <= HH) ? rowA + c0_ + 4 : e;                \
        const float* p2_ = (c0_ + 4 <= HH) ? rowB + c0_ : e;                    \
        const float* p3_ = (c0_ + 8 <= HH) ? rowB + c0_ + 4 : e;                \
        a0 = *reinterpret_cast<const float4v*>(p0_);                            \
        a1 = *reinterpret_cast<const float4v*>(p1_);                            \
        b0 = *reinterpret_cast<const float4v*>(p2_);                            \
        b1 = *reinterpret_cast<const float4v*>(p3_);                            \
    } while (0)

#define BODY(KS_) do {                                                          \
        short8 fa_ = pack8_cvt(a0, a1);                                         \
        short8 fb_ = pack8_cvt(b0, b1);                                         \
        if ((KS_) + 1 < NCH) LOAD_A((KS_) + 1);                                 \
        const ushort* bks_ = bb + (size_t)(KS_) * (GHF * 512) + lane * 8;       \
        _Pragma("unroll")                                                       \
        for (int f_ = 0; f_ < GHF; ++f_) {                                      \
            short8 bf_ = *reinterpret_cast<const short8*>(bks_ + f_ * 512);     \
            acc0[f_] = __builtin_amdgcn_mfma_f32_16x16x32_bf16(bf_, fa_, acc0[f_], 0, 0, 0); \
            acc1[f_] = __builtin_amdgcn_mfma_f32_16x16x32_bf16(bf_, fb_, acc1[f_], 0, 0, 0); \
        }                                                                       \
    } while (0)

    LOAD_A(0);
    BODY(0); BODY(1); BODY(2); BODY(3); BODY(4);
    BODY(5); BODY(6); BODY(7); BODY(8); BODY(9);
#undef BODY
#undef LOAD_A

    // ---- epilogue: out[m][g] = acc + Vx'[i][g] + Vx'[j][g]  (Ub folded in Vx') ----
    const int gb = gh * (GHF * 16);
#pragma unroll
    for (int t2 = 0; t2 < 2; ++t2) {
        int m = m0 + t2 * 16 + r;
        int j = m % NN;
        int ti = m / NN;        // b*NN + i
        int b = ti / NN;
        const float* vi = Vx + (size_t)ti * HH;
        const float* vj = Vx + (size_t)(b * NN + j) * HH;
        float* orow = out + (size_t)m * HH;
#pragma unroll
        for (int f = 0; f < GHF; ++f) {
            int g0 = gb + f * 16 + q * 4;
            if (g0 + 4 <= HH) {
                float4v v = t2 ? acc1[f] : acc0[f];
                float4v vi4 = *reinterpret_cast<const float4v*>(vi + g0);
                float4v vj4 = *reinterpret_cast<const float4v*>(vj + g0);
                *reinterpret_cast<float4v*>(orow + g0) = v + vi4 + vj4;
            }
        }
    }
}

extern "C" void kernel_launch(void* const* d_in, const int* in_sizes, int n_in,
                              void* d_out, int out_size, void* d_ws, size_t ws_size,
                              hipStream_t stream) {
    const float* x  = (const float*)d_in[0];
    const float* e  = (const float*)d_in[1];
    const float* Uw = (const float*)d_in[2];
    const float* Ub = (const float*)d_in[3];
    const float* Vw = (const float*)d_in[4];
    const float* Vb = (const float*)d_in[5];
    float* out = (float*)d_out;

    ushort* Bp = (ushort*)d_ws;                              // 204,800 B (frag-packed bf16 U_w)
    float*  Vx = (float*)((char*)d_ws + 204800);             // 960,000 B

    pack_u<<<50, 256, 0, stream>>>(Uw, Bp);
    vx_kernel<<<BB * NN, 256, 0, stream>>>(x, Vw, Vb, Ub, Vx);
    // 10000 wave-tasks (5000 tiles x 2 g-halves), 4 per block
    gemm_kernel<<<2500, 256, 0, stream>>>(e, Bp, Vx, out);
}

// Round 13
// 204.777 us; speedup vs baseline: 1.2836x; 1.2836x over previous
//
#include <hip/hip_runtime.h>
#include <hip/hip_bf16.h>

#define BB 4
#define NN 200
#define HH 300
#define NCH 10            // k-steps of 32 (K padded to 320)
#define GF 20             // g-frags of 16 (full G padded to 320)
#define GHF 10            // g-frags per g-half
#define NTILE 5000        // 32-row tiles
#define WS_BP    0
#define WS_BPF   204800
#define WS_VX    409600
#define WS_EBF   1369600
#define WS_NEED  (WS_EBF + 102400000ull)

typedef __attribute__((ext_vector_type(8))) short short8;
typedef __attribute__((ext_vector_type(4))) float float4v;

static __device__ __forceinline__ ushort f2bf(float x) {
    union { float f; uint u; } v; v.f = x;
    uint r = v.u + 0x7FFFu + ((v.u >> 16) & 1u);  // RNE
    return (ushort)(r >> 16);
}

static __device__ __forceinline__ short8 pack8_cvt(float4v a, float4v b) {
    uint u0, u1, u2, u3;
    asm("v_cvt_pk_bf16_f32 %0, %1, %2" : "=v"(u0) : "v"(a[0]), "v"(a[1]));
    asm("v_cvt_pk_bf16_f32 %0, %1, %2" : "=v"(u1) : "v"(a[2]), "v"(a[3]));
    asm("v_cvt_pk_bf16_f32 %0, %1, %2" : "=v"(u2) : "v"(b[0]), "v"(b[1]));
    asm("v_cvt_pk_bf16_f32 %0, %1, %2" : "=v"(u3) : "v"(b[2]), "v"(b[3]));
    union { uint u[4]; short8 s; } r;
    r.u[0] = u0; r.u[1] = u1; r.u[2] = u2; r.u[3] = u3;
    return r.s;
}

static __device__ __forceinline__ void gload_lds16(const void* g, void* l) {
    __builtin_amdgcn_global_load_lds(
        (const __attribute__((address_space(1))) unsigned int*)g,
        (__attribute__((address_space(3))) unsigned int*)l, 16, 0, 0);
}

// ---- U_w packers: g-half-major (two-pass path) and ks-major full-G (fallback) ----
__global__ void pack_u_gh(const float* __restrict__ Uw, ushort* __restrict__ Bp) {
    int idx = blockIdx.x * 256 + threadIdx.x;
    if (idx >= 2 * NCH * GHF * 64) return;
    int lane = idx & 63;
    int rem = idx >> 6;
    int fh = rem % GHF;
    int ks = (rem / GHF) % NCH;
    int gh = rem / (GHF * NCH);
    int g = (gh * GHF + fh) * 16 + (lane & 15);
    int h0 = ks * 32 + (lane >> 4) * 8;
    ushort v[8];
#pragma unroll
    for (int j = 0; j < 8; ++j) {
        int h = h0 + j;
        v[j] = (g < HH && h < HH) ? f2bf(Uw[g * HH + h]) : (ushort)0;
    }
    *reinterpret_cast<short8*>(Bp + (size_t)idx * 8) = *reinterpret_cast<const short8*>(v);
}

__global__ void pack_u_full(const float* __restrict__ Uw, ushort* __restrict__ Bp) {
    int idx = blockIdx.x * 256 + threadIdx.x;
    if (idx >= NCH * GF * 64) return;
    int lane = idx & 63;
    int kg = idx >> 6;
    int gf = kg % GF, ks = kg / GF;
    int g = gf * 16 + (lane & 15);
    int h0 = ks * 32 + (lane >> 4) * 8;
    ushort v[8];
#pragma unroll
    for (int j = 0; j < 8; ++j) {
        int h = h0 + j;
        v[j] = (g < HH && h < HH) ? f2bf(Uw[g * HH + h]) : (ushort)0;
    }
    *reinterpret_cast<short8*>(Bp + (size_t)idx * 8) = *reinterpret_cast<const short8*>(v);
}

// Vx[b,n,g] = x@Vw^T + Vb + 0.5*Ub  (Ub folded: vi'+vj' = vi+vj+Ub)
__global__ void vx_kernel(const float* __restrict__ x, const float* __restrict__ Vw,
                          const float* __restrict__ Vb, const float* __restrict__ Ub,
                          float* __restrict__ Vx) {
    __shared__ float xs[HH];
    int row = blockIdx.x;
    const float* xr = x + (size_t)row * HH;
    for (int h = threadIdx.x; h < HH; h += 256) xs[h] = xr[h];
    __syncthreads();
    for (int g = threadIdx.x; g < HH; g += 256) {
        const float4* wr = reinterpret_cast<const float4*>(Vw + (size_t)g * HH);
        const float4* xv = reinterpret_cast<const float4*>(xs);
        float s0 = 0.f, s1 = 0.f, s2 = 0.f, s3 = 0.f;
#pragma unroll 5
        for (int k = 0; k < HH / 4; ++k) {
            float4 w = wr[k];
            float4 xx = xv[k];
            s0 += w.x * xx.x; s1 += w.y * xx.y; s2 += w.z * xx.z; s3 += w.w * xx.w;
        }
        Vx[(size_t)row * HH + g] = Vb[g] + 0.5f * Ub[g] + s0 + s1 + s2 + s3;
    }
}

// ---- PASS 1: e f32 -> bf16, MFMA-frag order, K padded to 320 with zeros ----
// ebf byte offset = ((t*10 + ks)*2 + half)*1024 + lane*16
// elem j of lane: row = t*32 + half*16 + (lane&15), col = ks*32 + (lane>>4)*8 + j
__global__ void pack_e(const float* __restrict__ e, ushort* __restrict__ ebf) {
    int id = blockIdx.x * 256 + threadIdx.x;     // 0 .. 6,399,999
    int lane = id & 63;
    int rem = id >> 6;
    int half = rem & 1;
    int tks = rem >> 1;
    int ks = tks % NCH;
    int t = tks / NCH;
    int r = lane & 15, q = lane >> 4;
    int row = t * 32 + half * 16 + r;
    int c0 = ks * 32 + q * 8;
    const float* rp = e + (size_t)row * HH;
    const float* p0 = (c0 + 4 <= HH) ? rp + c0 : e;
    const float* p1 = (c0 + 8 <= HH) ? rp + c0 + 4 : e;
    float4v a = *reinterpret_cast<const float4v*>(p0);
    float4v b = *reinterpret_cast<const float4v*>(p1);
    short8 w = pack8_cvt(a, b);
    if (ks == NCH - 1) {
#pragma unroll
        for (int j = 0; j < 8; ++j)
            if (c0 + j >= HH) w[j] = 0;
    }
    *reinterpret_cast<short8*>(ebf + (size_t)id * 8) = w;
}

// ---- PASS 2: BM=128 x g-half, 512 thr (8 waves = 4 tiles x 2 halves), BK=64,
// 5 chunks, A (16 KB) + B (20 KB) double-buffered = 72 KB -> 2 blocks/CU.
// All staging via linear gload_lds; counted vmcnt(4); no cvt, no k-tail. ----
__launch_bounds__(512, 2)
__global__ void gemm2(const ushort* __restrict__ ebf, const ushort* __restrict__ Bp,
                      const float* __restrict__ Vx, float* __restrict__ out) {
    __shared__ __align__(16) ushort Aa[2][8192];    // 2 x 16 KB
    __shared__ __align__(16) ushort Bb[2][10240];   // 2 x 20 KB
    const int tid = threadIdx.x;
    const int w = tid >> 6, l = tid & 63;
    const int r = l & 15, q = l >> 4;
    const int gh = blockIdx.x & 1;
    const int mb = blockIdx.x >> 1;       // 0..1249
    const int m0 = mb * 128;
    const int t0 = mb * 4;                // first 32-row tile of this block
    const char* bbase = (const char*)Bp + (size_t)gh * 102400;

    float4v acc[GHF];
#pragma unroll
    for (int f = 0; f < GHF; ++f) acc[f] = (float4v){0.f, 0.f, 0.f, 0.f};

    // A chunk KC (ks = 2KC, 2KC+1): 2 rounds x 8 KB; round rd covers tiles t0+2rd..+1
#define STAGE_A(KC_, P_) do {                                                   \
        _Pragma("unroll")                                                       \
        for (int rd_ = 0; rd_ < 2; ++rd_) {                                     \
            int tile_ = t0 + rd_ * 2 + (tid >> 8);                              \
            const char* src_ = (const char*)ebf                                 \
                + ((size_t)(tile_ * NCH + 2 * (KC_)) * 2048) + (tid & 255) * 16;\
            gload_lds16(src_, (char*)&Aa[P_][0] + rd_ * 8192 + tid * 16);       \
        }                                                                       \
    } while (0)

    // B chunk KC: 20 KB contiguous; 2 full rounds + half round (waves 0-3)
#define STAGE_B(KC_, P_) do {                                                   \
        const char* bs_ = bbase + (size_t)(KC_) * 20480;                        \
        char* bd_ = (char*)&Bb[P_][0];                                          \
        gload_lds16(bs_ + tid * 16,        bd_ + tid * 16);                     \
        gload_lds16(bs_ + 8192 + tid * 16, bd_ + 8192 + tid * 16);              \
        if (tid < 256)                                                          \
            gload_lds16(bs_ + 16384 + tid * 16, bd_ + 16384 + tid * 16);        \
    } while (0)

    // 2 ks x 10 frags = 20 MFMA per wave; wave (tile w>>1, half w&1)
#define COMPUTE(P_) do {                                                        \
        const char* ab_ = (const char*)&Aa[P_][0] + (w >> 1) * 4096 + (w & 1) * 1024; \
        const char* bb_ = (const char*)&Bb[P_][0];                              \
        _Pragma("unroll")                                                       \
        for (int ki_ = 0; ki_ < 2; ++ki_) {                                     \
            short8 fa_ = *reinterpret_cast<const short8*>(ab_ + ki_ * 2048 + l * 16); \
            const char* bk_ = bb_ + ki_ * 10240 + l * 16;                       \
            _Pragma("unroll")                                                   \
            for (int f_ = 0; f_ < GHF; ++f_) {                                  \
                short8 bf_ = *reinterpret_cast<const short8*>(bk_ + f_ * 1024); \
                acc[f_] = __builtin_amdgcn_mfma_f32_16x16x32_bf16(bf_, fa_, acc[f_], 0, 0, 0); \
            }                                                                   \
        }                                                                       \
    } while (0)

#define WAITV(N_) do {                                                          \
        __builtin_amdgcn_sched_barrier(0);                                      \
        asm volatile("s_waitcnt vmcnt(" #N_ ")" ::: "memory");                  \
        __builtin_amdgcn_sched_barrier(0);                                      \
    } while (0)

#define BAR() do {                                                              \
        asm volatile("s_waitcnt lgkmcnt(0)" ::: "memory");                      \
        __builtin_amdgcn_s_barrier();                                           \
        __builtin_amdgcn_sched_barrier(0);                                      \
    } while (0)

    // batches/wave: A(2)+B(2 or 3) -> WAITV(4) always retires the whole prior batch
    STAGE_A(0, 0); STAGE_B(0, 0);
    STAGE_A(1, 1); STAGE_B(1, 1);
    WAITV(4); BAR();

    COMPUTE(0); BAR(); STAGE_A(2, 0); STAGE_B(2, 0); WAITV(4); BAR();
    COMPUTE(1); BAR(); STAGE_A(3, 1); STAGE_B(3, 1); WAITV(4); BAR();
    COMPUTE(0); BAR(); STAGE_A(4, 0); STAGE_B(4, 0); WAITV(4); BAR();
    COMPUTE(1); BAR(); WAITV(0); BAR();
    COMPUTE(0);

    // epilogue: out[m][g] = acc + Vx'[i][g] + Vx'[j][g]
    {
        const int m = m0 + (w >> 1) * 32 + (w & 1) * 16 + r;
        int j = m % NN;
        int ti = m / NN;
        int b = ti / NN;
        const float* vi = Vx + (size_t)ti * HH;
        const float* vj = Vx + (size_t)(b * NN + j) * HH;
        float* orow = out + (size_t)m * HH;
        const int gb = gh * (GHF * 16);
#pragma unroll
        for (int f = 0; f < GHF; ++f) {
            int g0 = gb + f * 16 + q * 4;
            if (g0 + 4 <= HH) {
                float4v vi4 = *reinterpret_cast<const float4v*>(vi + g0);
                float4v vj4 = *reinterpret_cast<const float4v*>(vj + g0);
                *reinterpret_cast<float4v*>(orow + g0) = acc[f] + vi4 + vj4;
            }
        }
    }
#undef STAGE_A
#undef STAGE_B
#undef COMPUTE
#undef WAITV
#undef BAR
}

// ---- FALLBACK: R11 kernel (proven 149.9 us total), used when ws is too small ----
__launch_bounds__(512, 2)
__global__ void gemm_fb(const float* __restrict__ e, const ushort* __restrict__ Bp,
                        const float* __restrict__ Vx, float* __restrict__ out) {
    __shared__ __align__(16) char SMEM[147456];
    const int tid = threadIdx.x;
    const int w = tid >> 6, l = tid & 63;
    const int r = l & 15, q = l >> 4;
    const int m0 = blockIdx.x * 128;

#define AFB(P_) (SMEM + (P_) * 32768)
#define BFB(P_) (SMEM + 65536 + (P_) * 40960)
#define WAITV(N_) asm volatile("s_waitcnt vmcnt(" #N_ ")" ::: "memory")
#define BAR() do {                                                   \
        __builtin_amdgcn_sched_barrier(0);                           \
        asm volatile("s_waitcnt lgkmcnt(0)" ::: "memory");           \
        __builtin_amdgcn_sched_barrier(0);                           \
        __builtin_amdgcn_s_barrier();                                \
        __builtin_amdgcn_sched_barrier(0);                           \
    } while (0)
#define STAGE_A(KC_, P_) do {                                                   \
        _Pragma("unroll")                                                       \
        for (int rd_ = 0; rd_ < 4; ++rd_) {                                     \
            int row_ = rd_ * 32 + w * 4 + (l >> 4);                             \
            int ucl_ = (l & 15) ^ (row_ & 15);                                  \
            const char* src_ = (const char*)(e + (size_t)(m0 + row_) * HH)      \
                               + (KC_) * 256 + ucl_ * 16;                       \
            if ((KC_) == 4 && ucl_ >= 11) src_ = (const char*)e;                \
            gload_lds16(src_, AFB(P_) + rd_ * 8192 + w * 1024 + l * 16);        \
        }                                                                       \
    } while (0)
#define STAGE_B(KC_, P_) do {                                                   \
        const char* bs_ = (const char*)Bp + (size_t)(KC_) * 40960;              \
        char* bd_ = BFB(P_);                                                    \
        _Pragma("unroll")                                                       \
        for (int rd_ = 0; rd_ < 5; ++rd_)                                       \
            gload_lds16(bs_ + rd_ * 8192 + tid * 16, bd_ + rd_ * 8192 + tid * 16); \
    } while (0)

    float4v acc[GF];
#pragma unroll
    for (int f = 0; f < GF; ++f) acc[f] = (float4v){0.f, 0.f, 0.f, 0.f};

#define COMPUTE(P_) do {                                                        \
        const char* ab_ = AFB(P_) + (w * 16 + r) * 256;                         \
        const ushort* bb_ = (const ushort*)BFB(P_);                             \
        _Pragma("unroll")                                                       \
        for (int s_ = 0; s_ < 2; ++s_) {                                        \
            int u0_ = (s_ * 8 + 2 * q) ^ r;                                     \
            int u1_ = (s_ * 8 + 2 * q + 1) ^ r;                                 \
            float4v fa0_ = *reinterpret_cast<const float4v*>(ab_ + u0_ * 16);   \
            float4v fa1_ = *reinterpret_cast<const float4v*>(ab_ + u1_ * 16);   \
            short8 fa_ = pack8_cvt(fa0_, fa1_);                                 \
            const ushort* bs_ = bb_ + s_ * (GF * 512) + l * 8;                  \
            _Pragma("unroll")                                                   \
            for (int f_ = 0; f_ < GF; ++f_) {                                   \
                short8 bfr_ = *reinterpret_cast<const short8*>(bs_ + f_ * 512); \
                acc[f_] = __builtin_amdgcn_mfma_f32_16x16x32_bf16(bfr_, fa_, acc[f_], 0, 0, 0); \
            }                                                                   \
        }                                                                       \
    } while (0)

    STAGE_A(0, 0); STAGE_B(0, 0);
    STAGE_A(1, 1); STAGE_B(1, 1);
    WAITV(9); BAR();
    COMPUTE(0); BAR(); STAGE_A(2, 0); STAGE_B(2, 0); WAITV(9); BAR();
    COMPUTE(1); BAR(); STAGE_A(3, 1); STAGE_B(3, 1); WAITV(9); BAR();
    COMPUTE(0); BAR(); STAGE_A(4, 0); STAGE_B(4, 0); WAITV(9); BAR();
    COMPUTE(1); BAR(); WAITV(0); BAR();
    COMPUTE(0);

    asm volatile("s_waitcnt lgkmcnt(0)" ::: "memory");
    __builtin_amdgcn_s_barrier();
    __builtin_amdgcn_sched_barrier(0);
    char* ep = SMEM + w * 10496;
    const int mbase = m0 + w * 16;
#pragma unroll
    for (int gh2 = 0; gh2 < 2; ++gh2) {
        if (gh2) { asm volatile("s_waitcnt lgkmcnt(0)" ::: "memory"); __builtin_amdgcn_sched_barrier(0); }
#pragma unroll
        for (int ff = 0; ff < 10; ++ff) {
            int f = gh2 * 10 + ff;
            if (f < 19)
                *reinterpret_cast<float4v*>(ep + r * 656 + ff * 64 + q * 16) = acc[f];
        }
        asm volatile("s_waitcnt lgkmcnt(0)" ::: "memory");
        __builtin_amdgcn_sched_barrier(0);
        const int nl = gh2 ? 35 : 40;
#pragma unroll 4
        for (int rr = 0; rr < 16; ++rr) {
            if (l < nl) {
                float4v v = *reinterpret_cast<const float4v*>(ep + rr * 656 + l * 16);
                int m = mbase + rr;
                int j = m % NN;
                int ti = m / NN;
                int b = ti / NN;
                int g0 = gh2 * 160 + l * 4;
                float4v vi4 = *reinterpret_cast<const float4v*>(Vx + (size_t)ti * HH + g0);
                float4v vj4 = *reinterpret_cast<const float4v*>(Vx + (size_t)(b * NN + j) * HH + g0);
                *reinterpret_cast<float4v*>(out + (size_t)m * HH + g0) = v + vi4 + vj4;
            }
        }
    }
#undef COMPUTE
#undef STAGE_A
#undef STAGE_B
#undef BAR
#undef WAITV
#undef AFB
#undef BFB
}

extern "C" void kernel_launch(void* const* d_in, const int* in_sizes, int n_in,
                              void* d_out, int out_size, void* d_ws, size_t ws_size,
                              hipStream_t stream) {
    const float* x  = (const float*)d_in[0];
    const float* e  = (const float*)d_in[1];
    const float* Uw = (const float*)d_in[2];
    const float* Ub = (const float*)d_in[3];
    const float* Vw = (const float*)d_in[4];
    const float* Vb = (const float*)d_in[5];
    float* out = (float*)d_out;

    ushort* Bp  = (ushort*)((char*)d_ws + WS_BP);    // g-half-major pack
    ushort* BpF = (ushort*)((char*)d_ws + WS_BPF);   // ks-major full-G pack (fallback)
    float*  Vx  = (float*)((char*)d_ws + WS_VX);
    ushort* ebf = (ushort*)((char*)d_ws + WS_EBF);   // 102.4 MB bf16 frag-packed e

    vx_kernel<<<BB * NN, 256, 0, stream>>>(x, Vw, Vb, Ub, Vx);

    if (ws_size >= WS_NEED) {
        pack_u_gh<<<50, 256, 0, stream>>>(Uw, Bp);
        pack_e<<<25000, 256, 0, stream>>>(e, ebf);
        gemm2<<<2500, 512, 0, stream>>>(ebf, Bp, Vx, out);
    } else {
        pack_u_full<<<50, 256, 0, stream>>>(Uw, BpF);
        gemm_fb<<<1250, 512, 0, stream>>>(e, BpF, Vx, out);
    }
}